// Round 9
// baseline (300.262 us; speedup 1.0000x reference)
//
#include <hip/hip_runtime.h>

#define N_NODES 50000
#define N_EDGES 800000
#define F 128
#define BF 256
#define NF (N_NODES * F)
#define CAP 32                        // slots per node (deg ~Poisson(16))
#define SPILL_CAP 65536
#define PRE_BLOCKS 3200
#define PRE_THREADS (PRE_BLOCKS * 256)

typedef __attribute__((ext_vector_type(8))) _Float16 half8;
typedef __attribute__((ext_vector_type(4))) _Float16 half4;
typedef __attribute__((ext_vector_type(4))) float floatx4;

// ========== build: one pass — slot-scatter edges + x,W -> fp16 ==============
__global__ __launch_bounds__(256) void k_build(const int* __restrict__ ei,
                                               const float* __restrict__ attr,
                                               const float* __restrict__ x,
                                               const float* __restrict__ W,
                                               int* __restrict__ cnt,       // [N+1], last = nspill
                                               uint4* __restrict__ spill,
                                               uint2* __restrict__ slots,   // [N][CAP]
                                               _Float16* __restrict__ xi,
                                               _Float16* __restrict__ Wh) {
    int t = blockIdx.x * 256 + threadIdx.x;
    if (t < N_EDGES) {
        int r = ei[t];
        int c = ei[N_EDGES + t];
        float a = attr[t];
        int slot = atomicAdd(&cnt[r], 1);
        if (slot < CAP) {
            slots[(size_t)r * CAP + slot] = make_uint2((unsigned)c, __float_as_uint(a));
        } else {
            int sp = atomicAdd(&cnt[N_NODES], 1);
            if (sp < SPILL_CAP)
                spill[sp] = make_uint4((unsigned)r, (unsigned)c, __float_as_uint(a), 0u);
        }
    }
    if (t < 4096) {                       // W (128x128 fp32) -> Wh fp16
        float4 w = *(const float4*)(W + t * 4);
        half4 h;
        h[0] = (_Float16)w.x; h[1] = (_Float16)w.y;
        h[2] = (_Float16)w.z; h[3] = (_Float16)w.w;
        *(half4*)(Wh + t * 4) = h;
    }
    // fused cvt: x[b][n][f] fp32 -> xi[n][b*128+f] fp16
    for (int i = t; i < 2 * NF / 4; i += PRE_THREADS) {
        size_t base = (size_t)i * 4;
        int b = (base >= (size_t)NF) ? 1 : 0;
        size_t rem = base - (size_t)b * NF;
        int n = (int)(rem >> 7);
        int f = (int)(rem & 127);
        float4 v = *(const float4*)(x + base);
        half4 h;
        h[0] = (_Float16)v.x; h[1] = (_Float16)v.y;
        h[2] = (_Float16)v.z; h[3] = (_Float16)v.w;
        *(half4*)(xi + (size_t)n * BF + b * F + f) = h;
    }
}

// ========== dinv[r] = rsqrt(1 + sum attr): one wave per row =================
__global__ __launch_bounds__(256) void k_deg_s(const int* __restrict__ cnt,
                                               const uint2* __restrict__ slots,
                                               const uint4* __restrict__ spill,
                                               float* __restrict__ dinv) {
    int r    = (int)(((size_t)blockIdx.x * 256 + threadIdx.x) >> 6);
    int lane = threadIdx.x & 63;
    if (r >= N_NODES) return;
    int cn = cnt[r];
    int m  = (cn < CAP) ? cn : CAP;
    float a = 0.0f;
    if (lane < m) a = __uint_as_float(slots[(size_t)r * CAP + lane].y);
    if (cn > CAP) {
        int ns = cnt[N_NODES]; if (ns > SPILL_CAP) ns = SPILL_CAP;
        for (int i = lane; i < ns; i += 64) {
            uint4 e = spill[i];
            if ((int)e.x == r) a += __uint_as_float(e.z);
        }
    }
    for (int off = 32; off > 0; off >>= 1) a += __shfl_down(a, off);
    if (lane == 0) dinv[r] = rsqrtf(a + 1.0f);
}

// ========== fused gather + MFMA GEMM + epilogue =============================
// block = 128 threads (2 waves), 16 rows. Phase 1: gather rows into LDS fp16.
// Phase 2: wave b computes out[b, n0..n0+15, :] = relu(A @ Wh^T + s*bias).
__global__ __launch_bounds__(128) void k_fused(const int* __restrict__ cnt,
                                               const uint2* __restrict__ slots,
                                               const uint4* __restrict__ spill,
                                               const _Float16* __restrict__ xi,
                                               const float* __restrict__ dinv,
                                               const _Float16* __restrict__ Wh,
                                               const float* __restrict__ bias,
                                               float* __restrict__ out) {
    __shared__ _Float16 sA[16 * 264];   // 16 rows x 256 feats (+8 pad)
    __shared__ float    sS[16];         // per-row s (sum of norms incl self)

    const int n0   = blockIdx.x * 16;   // 3125 * 16 == 50000 exactly
    const int wave = threadIdx.x >> 6;
    const int lane = threadIdx.x & 63;
    const int idx  = lane * 4;          // 0..252 over interleaved (b,f)

    // ---- phase 1: each wave gathers 8 rows ----
    for (int rr = 0; rr < 8; ++rr) {
        int nl = wave * 8 + rr;
        int r  = n0 + nl;
        int cn = cnt[r];
        int m  = (cn < CAP) ? cn : CAP;

        int   ec = 0;
        float pw = 0.0f;
        if (lane < m) {
            uint2 en = slots[(size_t)r * CAP + lane];
            ec = (int)en.x;
            pw = __uint_as_float(en.y) * dinv[ec];
        }

        float dinvr = dinv[r];
        float nm0   = dinvr * dinvr;
        half4 hv    = *(const half4*)(xi + (size_t)r * BF + idx);

        float4 acc = make_float4(0.f, 0.f, 0.f, 0.f);
        float sp = 0.0f;
        for (int j = 0; j < m; ++j) {
            int   c = __shfl(ec, j);
            float p = __shfl(pw, j);
            half4 v = *(const half4*)(xi + (size_t)c * BF + idx);
            acc.x += p * (float)v[0]; acc.y += p * (float)v[1];
            acc.z += p * (float)v[2]; acc.w += p * (float)v[3];
            sp += p;
        }
        if (cn > CAP) {                 // rare spill rows
            int ns = cnt[N_NODES]; if (ns > SPILL_CAP) ns = SPILL_CAP;
            for (int i = 0; i < ns; ++i) {
                uint4 e = spill[i];
                if ((int)e.x == r) {
                    int c = (int)e.y;
                    float p = __uint_as_float(e.z) * dinv[c];
                    half4 v = *(const half4*)(xi + (size_t)c * BF + idx);
                    acc.x += p * (float)v[0]; acc.y += p * (float)v[1];
                    acc.z += p * (float)v[2]; acc.w += p * (float)v[3];
                    sp += p;
                }
            }
        }

        half4 ho;
        ho[0] = (_Float16)(dinvr * acc.x + nm0 * (float)hv[0]);
        ho[1] = (_Float16)(dinvr * acc.y + nm0 * (float)hv[1]);
        ho[2] = (_Float16)(dinvr * acc.z + nm0 * (float)hv[2]);
        ho[3] = (_Float16)(dinvr * acc.w + nm0 * (float)hv[3]);
        *(half4*)&sA[nl * 264 + idx] = ho;
        if (lane == 0) sS[nl] = dinvr * sp + nm0;
    }
    __syncthreads();

    // ---- phase 2: wave `wave` handles batch b = wave ----
    const int bb   = wave;
    const int ln   = lane & 15;
    const int quad = lane >> 4;

    floatx4 acc[8];
    for (int ot = 0; ot < 8; ++ot) acc[ot] = (floatx4){0.f, 0.f, 0.f, 0.f};

    for (int k0 = 0; k0 < 4; ++k0) {
        half8 a = *(const half8*)&sA[ln * 264 + bb * 128 + k0 * 32 + quad * 8];
        for (int ot = 0; ot < 8; ++ot) {
            half8 bf = *(const half8*)(Wh + (ot * 16 + ln) * 128 + k0 * 32 + quad * 8);
            acc[ot] = __builtin_amdgcn_mfma_f32_16x16x32_f16(a, bf, acc[ot], 0, 0, 0);
        }
    }

    float sv[4];
    for (int rg = 0; rg < 4; ++rg) sv[rg] = sS[quad * 4 + rg];
    float* ob = out + (size_t)bb * NF;
    for (int ot = 0; ot < 8; ++ot) {
        int o = ot * 16 + ln;
        float bo = bias[o];
        for (int rg = 0; rg < 4; ++rg) {
            int n = n0 + quad * 4 + rg;
            float v = acc[ot][rg] + sv[rg] * bo;
            ob[(size_t)n * F + o] = fmaxf(v, 0.0f);
        }
    }
}

// ========== atomic fallback pieces (tiny ws) ================================
__global__ void k_deg(const int* __restrict__ ei, const float* __restrict__ attr,
                      float* __restrict__ deg) {
    int e = blockIdx.x * 256 + threadIdx.x;
    if (e < N_EDGES) atomicAdd(&deg[ei[e]], attr[e]);
}
__global__ void k_dinv(float* __restrict__ deg) {
    int n = blockIdx.x * 256 + threadIdx.x;
    if (n < N_NODES) deg[n] = rsqrtf(deg[n] + 1.0f);
}
__global__ __launch_bounds__(256) void k_edge(const int* __restrict__ ei,
                                              const float* __restrict__ attr,
                                              const float* __restrict__ dinv,
                                              const float* __restrict__ x,
                                              float* __restrict__ out,
                                              float* __restrict__ s) {
    int e    = (int)(((size_t)blockIdx.x * 256 + threadIdx.x) >> 6);
    int lane = threadIdx.x & 63;
    if (e >= N_EDGES) return;
    int r = ei[e];
    int c = ei[N_EDGES + e];
    float norm = dinv[r] * attr[e] * dinv[c];
    if (lane == 0) atomicAdd(&s[r], norm);
    int idx = lane * 4;
    int b = idx >> 7;
    int f = idx & 127;
    float4 v = *(const float4*)(x + (size_t)b * NF + (size_t)c * F + f);
    float* dst = out + (size_t)b * NF + (size_t)r * F + f;
    atomicAdd(dst + 0, norm * v.x);
    atomicAdd(dst + 1, norm * v.y);
    atomicAdd(dst + 2, norm * v.z);
    atomicAdd(dst + 3, norm * v.w);
}
__global__ void k_self(const float* __restrict__ x, const float* __restrict__ dinv,
                       float* __restrict__ out) {
    int i = blockIdx.x * 256 + threadIdx.x;
    if (i >= 2 * NF / 4) return;
    size_t base = (size_t)i * 4;
    int b = (base >= (size_t)NF) ? 1 : 0;
    size_t rem = base - (size_t)b * NF;
    int n = (int)(rem >> 7);
    float dn = dinv[n]; float sc = dn * dn;
    float4 v = *(const float4*)(x + base);
    float4* op = (float4*)(out + base);
    float4 o = *op;
    o.x += sc * v.x; o.y += sc * v.y; o.z += sc * v.z; o.w += sc * v.w;
    *op = o;
}
__global__ void k_sfix(const float* __restrict__ dinv, float* __restrict__ s) {
    int n = blockIdx.x * 256 + threadIdx.x;
    if (n < N_NODES) { float dn = dinv[n]; s[n] += dn * dn; }
}

// ========== fallback GEMM (in-place on fp32 out, A via LDS) =================
__global__ __launch_bounds__(256) void k_gemm1(const float* __restrict__ W,
                                               const float* __restrict__ bias,
                                               const float* __restrict__ s,
                                               float* __restrict__ out) {
    __shared__ _Float16 sW[128 * 136];
    __shared__ _Float16 sA[64 * 136];
    const int tid = threadIdx.x;
    const int b   = blockIdx.y;
    const int n0  = blockIdx.x * 64;
    float* ob = out + (size_t)b * NF;

    for (int i = 0; i < 16; ++i) {
        int idx = (i * 256 + tid) * 4;
        int o = idx >> 7, k = idx & 127;
        float4 w = *(const float4*)(W + idx);
        half4 h;
        h[0] = (_Float16)w.x; h[1] = (_Float16)w.y;
        h[2] = (_Float16)w.z; h[3] = (_Float16)w.w;
        *(half4*)&sW[o * 136 + k] = h;
    }
    for (int i = 0; i < 8; ++i) {
        int idx = (i * 256 + tid) * 4;
        int nl = idx >> 7, k = idx & 127;
        int n = n0 + nl;
        half4 h = {(_Float16)0.f, (_Float16)0.f, (_Float16)0.f, (_Float16)0.f};
        if (n < N_NODES) {
            float4 v = *(const float4*)(ob + (size_t)n * F + k);
            h[0] = (_Float16)v.x; h[1] = (_Float16)v.y;
            h[2] = (_Float16)v.z; h[3] = (_Float16)v.w;
        }
        *(half4*)&sA[nl * 136 + k] = h;
    }
    __syncthreads();

    const int wave = tid >> 6, lane = tid & 63;
    const int ln = lane & 15, quad = lane >> 4;
    const int nw = wave * 16;
    if (n0 + nw >= N_NODES) return;

    floatx4 acc[8];
    for (int ot = 0; ot < 8; ++ot) acc[ot] = (floatx4){0.f, 0.f, 0.f, 0.f};

    for (int k0 = 0; k0 < 4; ++k0) {
        half8 a = *(const half8*)&sA[(nw + ln) * 136 + k0 * 32 + quad * 8];
        for (int ot = 0; ot < 8; ++ot) {
            half8 bf = *(const half8*)&sW[(ot * 16 + ln) * 136 + k0 * 32 + quad * 8];
            acc[ot] = __builtin_amdgcn_mfma_f32_16x16x32_f16(a, bf, acc[ot], 0, 0, 0);
        }
    }

    float sv[4];
    for (int rg = 0; rg < 4; ++rg) sv[rg] = s[n0 + nw + quad * 4 + rg];
    for (int ot = 0; ot < 8; ++ot) {
        int o = ot * 16 + ln;
        float bo = bias[o];
        for (int rg = 0; rg < 4; ++rg) {
            int n = n0 + nw + quad * 4 + rg;
            float v = acc[ot][rg] + sv[rg] * bo;
            ob[(size_t)n * F + o] = fmaxf(v, 0.0f);
        }
    }
}

extern "C" void kernel_launch(void* const* d_in, const int* in_sizes, int n_in,
                              void* d_out, int out_size, void* d_ws, size_t ws_size,
                              hipStream_t stream) {
    const float* x    = (const float*)d_in[0];
    const int*   ei   = (const int*)d_in[1];
    const float* attr = (const float*)d_in[2];
    const float* W    = (const float*)d_in[3];
    const float* bias = (const float*)d_in[4];
    float* out = (float*)d_out;

    // ws layout: cnt[N+1] | dinv[N] | s[N] | Wh[16384]*2B | pad16 |
    //            spill[SPILL_CAP]*16B | slots[N*CAP]*8B | xi[2NF]*2B
    int*   cnt  = (int*)d_ws;
    float* dinv = (float*)(cnt + N_NODES + 1);
    float* s    = dinv + N_NODES;
    _Float16* Wh = (_Float16*)(s + N_NODES);
    size_t spill_off = ((size_t)((char*)(Wh + 16384) - (char*)d_ws) + 15) & ~(size_t)15;
    uint4* spill = (uint4*)((char*)d_ws + spill_off);
    size_t slots_off = spill_off + (size_t)SPILL_CAP * 16;
    uint2* slots = (uint2*)((char*)d_ws + slots_off);
    size_t xi_off = slots_off + (size_t)N_NODES * CAP * 8;
    _Float16* xi = (_Float16*)((char*)d_ws + xi_off);
    size_t need = xi_off + (size_t)2 * NF * 2;     // ~40 MB

    if (ws_size >= need) {
        hipMemsetAsync(cnt, 0, (N_NODES + 1) * sizeof(int), stream);
        k_build<<<PRE_BLOCKS, 256, 0, stream>>>(ei, attr, x, W, cnt, spill, slots, xi, Wh);
        size_t rthreads = (size_t)N_NODES * 64;
        k_deg_s<<<(unsigned)((rthreads + 255) / 256), 256, 0, stream>>>(cnt, slots, spill, dinv);
        k_fused<<<N_NODES / 16, 128, 0, stream>>>(cnt, slots, spill, xi, dinv, Wh, bias, out);
    } else {
        // atomic fallback: needs dinv[N]+s[N] only
        hipMemsetAsync(dinv, 0, N_NODES * sizeof(float), stream);
        hipMemsetAsync(s, 0, N_NODES * sizeof(float), stream);
        hipMemsetAsync(out, 0, (size_t)2 * NF * sizeof(float), stream);
        k_deg<<<(N_EDGES + 255) / 256, 256, 0, stream>>>(ei, attr, dinv);
        k_dinv<<<(N_NODES + 255) / 256, 256, 0, stream>>>(dinv);
        size_t edge_threads = (size_t)N_EDGES * 64;
        k_edge<<<(unsigned)((edge_threads + 255) / 256), 256, 0, stream>>>(
            ei, attr, dinv, x, out, s);
        k_self<<<(2 * NF / 4 + 255) / 256, 256, 0, stream>>>(x, dinv, out);
        k_sfix<<<(N_NODES + 255) / 256, 256, 0, stream>>>(dinv, s);
        dim3 gg((N_NODES + 63) / 64, 2);
        k_gemm1<<<gg, 256, 0, stream>>>(W, bias, s, out);
    }
}